// Round 1
// baseline (419.081 us; speedup 1.0000x reference)
//
#include <hip/hip_runtime.h>

// LSTM: B=8192, T=512, H=32. Block = 128 threads (2 waves) per 16-batch group;
// 512 blocks -> 2 blocks/CU, 4 waves/CU (1/SIMD). Each wave owns tiles
// t8 = 4w+tt (tt=0..3) of the transposed MFMA D = W'*h via
// mfma_f32_16x16x32_f16: tile t8 row m = (gate m&3, unit 8*(m>>2)+t8);
// C/D layout: lane (c,q) reg r = gate r of cell (unit 8q+t8, batch c).
// KEY: D->B identity. B-frag element j = h[unit 8q+j][batch c] at lane (c,q),
// so the 4 h's a wave computes (units 8q+4w+tt) are exactly elements 4w..4w+3
// of next step's B-frag, in-lane. Only the partner wave's 4 elements cross.
// Exchange: fused per-lane row hx[parity][lane][12 ints] (48B stride: b128
// reads conflict-free, 16B-aligned): ints 0-3 = BH (hi, units 8q+0..7),
// ints 4-7 = BL (lo). Wave w writes its quarters as 2x b64; each wave reads
// the fully-assembled BH/BL as 2x b128. One barrier/step, 2-wave scope.
// FP16 2-TERM scheme: weights single fp16, h split hi/lo fp16 (2 chained
// MFMAs per tile). Gates pre-scaled by -log2e (i,f,o) / +2log2e (g);
// cell math per lane vectorized f32x4 over tt: 20 exp2 + 8 rcp per step.

#define TT 512
#define HH 32
#define L2E 1.44269504088896340736f
#define XROW 132   // x tile row stride (floats): bank (4c+t) mod 32 -> 2-way

typedef _Float16 f16x8 __attribute__((ext_vector_type(8)));
typedef __fp16 fp16x2 __attribute__((ext_vector_type(2)));
typedef float f32x4 __attribute__((ext_vector_type(4)));

__device__ __forceinline__ float fastrcp(float x) { return __builtin_amdgcn_rcpf(x); }
__device__ __forceinline__ float exp2f_(float x) { return __builtin_amdgcn_exp2f(x); }

__launch_bounds__(128)
__global__ void lstm_kernel(const float* __restrict__ x,
                            const float* __restrict__ W_ih,
                            const float* __restrict__ W_hh,
                            const float* __restrict__ b_ih,
                            const float* __restrict__ b_hh,
                            const float* __restrict__ W_fc,
                            const float* __restrict__ b_fc,
                            float* __restrict__ out) {
    __shared__ int hx[2][64][12];        // [parity][lane][BH(4) BL(4) pad(4)]
    __shared__ float xbuf[16 * XROW];

    const int tid  = threadIdx.x;
    const int lane = tid & 63;
    const int w    = tid >> 6;        // wave 0/1: owns tiles 4w+tt
    const int c    = lane & 15;       // batch (MFMA n); also A m-row
    const int q    = lane >> 4;       // quad: k-block 8q; unit-block 8q
    const int base = blockIdx.x * 16;

    // ---- A-fragments (weights) for tiles 4w+tt, single fp16 ----
    const int gate = c & 3;
    const float asc = (gate == 2) ? (2.0f * L2E) : (-L2E);
    const int wrow0 = gate * 32 + 8 * (c >> 2);
    f16x8 wa[4];
    #pragma unroll
    for (int tt = 0; tt < 4; ++tt) {
        const int t8 = 4 * w + tt;
        #pragma unroll
        for (int j = 0; j < 8; ++j)
            wa[tt][j] = (_Float16)(W_hh[(wrow0 + t8) * HH + 8 * q + j] * asc);
    }

    // ---- per-cell consts: cell tt = (unit 8q + 4w + tt, batch c) ----
    f32x4 wih[4], bcs[4];
    #pragma unroll
    for (int tt = 0; tt < 4; ++tt) {
        const int u = 8 * q + 4 * w + tt;
        #pragma unroll
        for (int r = 0; r < 4; ++r) {
            const float sc = (r == 2) ? (2.0f * L2E) : (-L2E);
            wih[tt][r] = W_ih[32 * r + u] * sc;
            bcs[tt][r] = (b_ih[32 * r + u] + b_hh[32 * r + u]) * sc;
        }
    }

    // ---- init parity-0 exchange rows to zero (h0 = 0) ----
    {
        int2 z; z.x = 0; z.y = 0;
        *(int2*)&hx[0][lane][2 * w]     = z;   // hi quarter
        *(int2*)&hx[0][lane][4 + 2 * w] = z;   // lo quarter
    }

    f32x4 cs = {0.f, 0.f, 0.f, 0.f};     // c-state for cells tt=0..3

    // x staging: 16 rows x 128 floats, 512 float4 over 128 threads (4 each)
    const int xrow = tid >> 3;            // 0..15
    const int xcol = (tid & 7) * 4;

    auto step = [&](int t, int RP, int WP) {
        const f16x8 BH = *(const f16x8*)&hx[RP][lane][0];
        const f16x8 BL = *(const f16x8*)&hx[RP][lane][4];
        const float xc = xbuf[c * XROW + (t & 127)];
        f32x4 acc[4];
        #pragma unroll
        for (int tt = 0; tt < 4; ++tt) {
            f32x4 a = wih[tt] * xc + bcs[tt];
            acc[tt] = __builtin_amdgcn_mfma_f32_16x16x32_f16(wa[tt], BH, a, 0, 0, 0);
        }
        #pragma unroll
        for (int tt = 0; tt < 4; ++tt)
            acc[tt] = __builtin_amdgcn_mfma_f32_16x16x32_f16(wa[tt], BL, acc[tt], 0, 0, 0);

        f32x4 Ei, Ef, G, Eo;
        #pragma unroll
        for (int tt = 0; tt < 4; ++tt) {
            Ei[tt] = exp2f_(acc[tt][0]);
            Ef[tt] = exp2f_(acc[tt][1]);
            G[tt]  = exp2f_(acc[tt][2]);
            Eo[tt] = exp2f_(acc[tt][3]);
        }
        const f32x4 one = {1.f, 1.f, 1.f, 1.f};
        const f32x4 aig = (one + Ei) * (G + one);
        const f32x4 af  = one + Ef;
        const f32x4 num = cs * aig + (G - one) * af;
        const f32x4 den = af * aig;
        f32x4 rc;
        #pragma unroll
        for (int tt = 0; tt < 4; ++tt) rc[tt] = fastrcp(den[tt]);
        const f32x4 cn = num * rc;
        cs = cn;
        f32x4 yc = cn * (2.0f * L2E);
        #pragma unroll
        for (int tt = 0; tt < 4; ++tt)
            yc[tt] = __builtin_amdgcn_fmed3f(yc[tt], -60.f, 60.f);
        f32x4 C;
        #pragma unroll
        for (int tt = 0; tt < 4; ++tt) C[tt] = exp2f_(yc[tt]);
        const f32x4 hden = (C + one) * (one + Eo);
        f32x4 hr;
        #pragma unroll
        for (int tt = 0; tt < 4; ++tt) hr[tt] = fastrcp(hden[tt]);
        const f32x4 hv = (C - one) * hr;

        union PK { fp16x2 v; int i; _Float16 e[2]; };
        PK h01, h23, l01, l23;
        h01.v = __builtin_amdgcn_cvt_pkrtz(hv[0], hv[1]);
        h23.v = __builtin_amdgcn_cvt_pkrtz(hv[2], hv[3]);
        int2 whi; whi.x = h01.i; whi.y = h23.i;
        *(int2*)&hx[WP][lane][2 * w] = whi;       // hi out early, overlaps lo calc
        l01.v = __builtin_amdgcn_cvt_pkrtz(hv[0] - (float)h01.e[0],
                                           hv[1] - (float)h01.e[1]);
        l23.v = __builtin_amdgcn_cvt_pkrtz(hv[2] - (float)h23.e[0],
                                           hv[3] - (float)h23.e[1]);
        int2 wlo; wlo.x = l01.i; wlo.y = l23.i;
        *(int2*)&hx[WP][lane][4 + 2 * w] = wlo;
        __syncthreads();
    };

    for (int t = 0; t < TT; t += 2) {
        if ((t & 127) == 0) {
            // prev step ended with a barrier (or start of kernel): xbuf free
            #pragma unroll
            for (int s = 0; s < 4; ++s) {
                const float4 v = *(const float4*)&x[(base + xrow) * TT + t + xcol + 32 * s];
                *(float4*)&xbuf[xrow * XROW + xcol + 32 * s] = v;
            }
            __syncthreads();   // also orders the hx zero-init at t=0
        }
        step(t,     0, 1);     // read parity 0 (h(t)), write parity 1 (h(t+1))
        step(t + 1, 1, 0);     // read parity 1, write parity 0
    }
    // T even -> final h(512) fully assembled in parity-0 rows; loop ended with
    // a barrier, so reads below are safe.

    // ---- head: out[b] = h_T @ W_fc^T + b_fc ----
    {
        const f16x8 BH = *(const f16x8*)&hx[0][lane][0];
        const f16x8 BL = *(const f16x8*)&hx[0][lane][4];
        float s = 0.f;
        #pragma unroll
        for (int j = 0; j < 8; ++j)
            s += ((float)BH[j] + (float)BL[j]) * W_fc[8 * q + j];
        // reduce over q (lanes c, c+16, c+32, c+48) within the wave
        s += __shfl_xor(s, 16);
        s += __shfl_xor(s, 32);
        if (tid < 16)                         // wave 0 holds full sums
            out[base + tid] = b_fc[0] + s;
    }
}

extern "C" void kernel_launch(void* const* d_in, const int* in_sizes, int n_in,
                              void* d_out, int out_size, void* d_ws, size_t ws_size,
                              hipStream_t stream) {
    const float* x    = (const float*)d_in[0];
    const float* W_ih = (const float*)d_in[1];
    const float* W_hh = (const float*)d_in[2];
    const float* b_ih = (const float*)d_in[3];
    const float* b_hh = (const float*)d_in[4];
    const float* W_fc = (const float*)d_in[5];
    const float* b_fc = (const float*)d_in[6];
    float* out = (float*)d_out;

    const int B = 8192;
    lstm_kernel<<<B / 16, 128, 0, stream>>>(x, W_ih, W_hh, b_ih, b_hh,
                                            W_fc, b_fc, out);
}

// Round 2
// 402.831 us; speedup vs baseline: 1.0403x; 1.0403x over previous
//
#include <hip/hip_runtime.h>

// LSTM: B=8192, T=512, H=32 — FULLY IN-REGISTER recurrence, ZERO barriers.
// One wave per 16-batch group: 512 one-wave blocks (64 thr) -> 2 waves/CU on
// separate SIMDs, fully independent (no convoying).
// Transposed MFMA D = W'*h via mfma_f32_16x16x32_f16, 8 M-tiles per wave.
// D->B identity: tile t8's D at lane (c,q) reg r = gate r of (unit 8q+t8,
// batch c); B-frag element j at lane (c,q) = h[unit 8q+j][batch c].
// => the 8 h values a lane computes (hv[0..7], one per tile) ARE its own
// next-step B-fragment, same lane, element-for-element. The recurrence never
// leaves the register file. LDS only stages x (wave-private, lgkmcnt-ordered).
// FP16 2-TERM h (hi+lo, 2 chained MFMAs per tile) with single-fp16 weights.
// Gates pre-scaled by -log2e (i,f,o) / +2log2e (g); cell math vectorized
// f32x8 across the lane's 8 cells: 40 exp2 + 16 rcp + ~70 pk-VALU per step.

#define TT 512
#define HH 32
#define L2E 1.44269504088896340736f
#define XROW 132   // x tile row stride (floats): bank (4c+t) mod 32 -> 2-way

typedef _Float16 f16x8 __attribute__((ext_vector_type(8)));
typedef __fp16 fp16x2 __attribute__((ext_vector_type(2)));
typedef float f32x4 __attribute__((ext_vector_type(4)));
typedef float f32x8 __attribute__((ext_vector_type(8)));

__device__ __forceinline__ float fastrcp(float x) { return __builtin_amdgcn_rcpf(x); }
__device__ __forceinline__ float exp2f_(float x) { return __builtin_amdgcn_exp2f(x); }

__launch_bounds__(64)
__global__ void lstm_kernel(const float* __restrict__ x,
                            const float* __restrict__ W_ih,
                            const float* __restrict__ W_hh,
                            const float* __restrict__ b_ih,
                            const float* __restrict__ b_hh,
                            const float* __restrict__ W_fc,
                            const float* __restrict__ b_fc,
                            float* __restrict__ out) {
    __shared__ float xbuf[16 * XROW];     // x chunk: 16 batches x 128 steps

    const int lane = threadIdx.x & 63;
    const int c    = lane & 15;           // batch (MFMA n); also A m-row
    const int q    = lane >> 4;           // quad: k-block 8q; unit-block 8q
    const int base = blockIdx.x * 16;

    // ---- A-fragments (weights) for tiles 0..7, single fp16 ----
    const int gate = c & 3;
    const float asc = (gate == 2) ? (2.0f * L2E) : (-L2E);
    const int wrow0 = gate * 32 + 8 * (c >> 2);
    f16x8 wa[8];
    #pragma unroll
    for (int t8 = 0; t8 < 8; ++t8) {
        #pragma unroll
        for (int j = 0; j < 8; ++j)
            wa[t8][j] = (_Float16)(W_hh[(wrow0 + t8) * HH + 8 * q + j] * asc);
    }

    // ---- per-cell consts: cell tt = (unit 8q + tt, batch c) ----
    f32x4 wih[8], bcs[8];
    #pragma unroll
    for (int tt = 0; tt < 8; ++tt) {
        const int u = 8 * q + tt;
        #pragma unroll
        for (int r = 0; r < 4; ++r) {
            const float sc = (r == 2) ? (2.0f * L2E) : (-L2E);
            wih[tt][r] = W_ih[32 * r + u] * sc;
            bcs[tt][r] = (b_ih[32 * r + u] + b_hh[32 * r + u]) * sc;
        }
    }

    // ---- persistent recurrent state (all registers) ----
    union BF { int4 i4; f16x8 h; };
    BF bh, bl;                              // B-frags: h hi / h lo, fp16
    bh.i4 = make_int4(0, 0, 0, 0);
    bl.i4 = make_int4(0, 0, 0, 0);
    f32x8 cs = {0.f,0.f,0.f,0.f,0.f,0.f,0.f,0.f};   // c-state, cells 0..7
    f32x8 hv = {0.f,0.f,0.f,0.f,0.f,0.f,0.f,0.f};   // h (f32), cells 0..7

    // x staging geometry: 512 float4 per 128-step chunk over 64 lanes
    const int xr0 = lane >> 5;              // 0..1
    const int xc4 = (lane & 31) * 4;        // 0..124

    // stage chunk 0 (wave-private LDS: no barrier, lgkmcnt orders it)
    #pragma unroll
    for (int s = 0; s < 8; ++s) {
        const float4 v = *(const float4*)&x[(size_t)(base + xr0 + 2 * s) * TT + xc4];
        *(float4*)&xbuf[(xr0 + 2 * s) * XROW + xc4] = v;
    }
    float2 xc2 = *(const float2*)&xbuf[c * XROW];    // x for t=0,1

    auto STEP = [&](float xc) {
        f32x4 acc[8];
        #pragma unroll
        for (int tt = 0; tt < 8; ++tt) {
            f32x4 a = wih[tt] * xc + bcs[tt];
            acc[tt] = __builtin_amdgcn_mfma_f32_16x16x32_f16(wa[tt], bh.h, a, 0, 0, 0);
        }
        #pragma unroll
        for (int tt = 0; tt < 8; ++tt)
            acc[tt] = __builtin_amdgcn_mfma_f32_16x16x32_f16(wa[tt], bl.h, acc[tt], 0, 0, 0);

        f32x8 Ei, Ef, G, Eo;
        #pragma unroll
        for (int tt = 0; tt < 8; ++tt) {
            Ei[tt] = exp2f_(acc[tt][0]);
            Ef[tt] = exp2f_(acc[tt][1]);
            G[tt]  = exp2f_(acc[tt][2]);
            Eo[tt] = exp2f_(acc[tt][3]);
        }
        const f32x8 one = {1.f,1.f,1.f,1.f,1.f,1.f,1.f,1.f};
        const f32x8 aig = (one + Ei) * (G + one);
        const f32x8 af  = one + Ef;
        const f32x8 num = cs * aig + (G - one) * af;
        const f32x8 den = af * aig;
        f32x8 rc;
        #pragma unroll
        for (int tt = 0; tt < 8; ++tt) rc[tt] = fastrcp(den[tt]);
        cs = num * rc;
        f32x8 yc = cs * (2.0f * L2E);
        #pragma unroll
        for (int tt = 0; tt < 8; ++tt)
            yc[tt] = __builtin_amdgcn_fmed3f(yc[tt], -60.f, 60.f);
        f32x8 C;
        #pragma unroll
        for (int tt = 0; tt < 8; ++tt) C[tt] = exp2f_(yc[tt]);
        const f32x8 hden = (C + one) * (one + Eo);
        f32x8 hr;
        #pragma unroll
        for (int tt = 0; tt < 8; ++tt) hr[tt] = fastrcp(hden[tt]);
        hv = (C - one) * hr;

        // pack next B-frags: hi first (feeds next step's first MFMAs), lo after
        union PK { fp16x2 v; int i; _Float16 e[2]; };
        PK p0, p1, p2, p3, l0, l1, l2, l3;
        p0.v = __builtin_amdgcn_cvt_pkrtz(hv[0], hv[1]);
        p1.v = __builtin_amdgcn_cvt_pkrtz(hv[2], hv[3]);
        p2.v = __builtin_amdgcn_cvt_pkrtz(hv[4], hv[5]);
        p3.v = __builtin_amdgcn_cvt_pkrtz(hv[6], hv[7]);
        bh.i4 = make_int4(p0.i, p1.i, p2.i, p3.i);
        l0.v = __builtin_amdgcn_cvt_pkrtz(hv[0] - (float)p0.e[0], hv[1] - (float)p0.e[1]);
        l1.v = __builtin_amdgcn_cvt_pkrtz(hv[2] - (float)p1.e[0], hv[3] - (float)p1.e[1]);
        l2.v = __builtin_amdgcn_cvt_pkrtz(hv[4] - (float)p2.e[0], hv[5] - (float)p2.e[1]);
        l3.v = __builtin_amdgcn_cvt_pkrtz(hv[6] - (float)p3.e[0], hv[7] - (float)p3.e[1]);
        bl.i4 = make_int4(l0.i, l1.i, l2.i, l3.i);
    };

    #pragma unroll 1
    for (int t = 0; t < TT; t += 2) {
        if (t && (t & 127) == 0) {
            // restage next 128-step x chunk (reads of old chunk are done;
            // same-wave program order + lgkmcnt keep this race-free)
            #pragma unroll
            for (int s = 0; s < 8; ++s) {
                const float4 v = *(const float4*)&x[(size_t)(base + xr0 + 2 * s) * TT + t + xc4];
                *(float4*)&xbuf[(xr0 + 2 * s) * XROW + xc4] = v;
            }
            xc2 = *(const float2*)&xbuf[c * XROW];
        }
        // prefetch next pair of x values (discarded at chunk boundary)
        const float2 xnext = *(const float2*)&xbuf[c * XROW + ((t + 2) & 127)];
        STEP(xc2.x);
        STEP(xc2.y);
        xc2 = xnext;
    }

    // ---- head: out[b] = h_T @ W_fc^T + b_fc; hv holds h_T in full f32 ----
    {
        float s = 0.f;
        #pragma unroll
        for (int j = 0; j < 8; ++j)
            s += hv[j] * W_fc[8 * q + j];
        // reduce over q (lanes c, c+16, c+32, c+48)
        s += __shfl_xor(s, 16);
        s += __shfl_xor(s, 32);
        if (lane < 16)
            out[base + lane] = b_fc[0] + s;
    }
}

extern "C" void kernel_launch(void* const* d_in, const int* in_sizes, int n_in,
                              void* d_out, int out_size, void* d_ws, size_t ws_size,
                              hipStream_t stream) {
    const float* x    = (const float*)d_in[0];
    const float* W_ih = (const float*)d_in[1];
    const float* W_hh = (const float*)d_in[2];
    const float* b_ih = (const float*)d_in[3];
    const float* b_hh = (const float*)d_in[4];
    const float* W_fc = (const float*)d_in[5];
    const float* b_fc = (const float*)d_in[6];
    float* out = (float*)d_out;

    const int B = 8192;
    lstm_kernel<<<B / 16, 64, 0, stream>>>(x, W_ih, W_hh, b_ih, b_hh,
                                           W_fc, b_fc, out);
}

// Round 3
// 275.628 us; speedup vs baseline: 1.5205x; 1.4615x over previous
//
#include <hip/hip_runtime.h>

// LSTM: B=8192, T=512, H=32. Block = 512 threads (8 waves) per 16-batch group;
// 512 blocks -> 2 blocks/CU, 16 waves/CU (4/SIMD) — max trans-pipe coverage
// and 4-way per-SIMD interleave to hide the barrier convoy (R0 baseline: 2/SIMD
// = 66% duty; R1/R2 showed 1/SIMD exposes ~2x stall).
// Transposed MFMA D = W'*h via mfma_f32_16x16x32_f16. Wave w owns tile t8=w:
// D at lane (c,q) reg r = gate r of cell (unit 8q+w, batch c) -> exactly ONE
// cell per lane. B-frag element j at lane (c,q) = h[unit 8q+j][batch c] ->
// natural-order planes h[batch][unit] fp16, rows padded to HROW=40 (80 B:
// 16B-aligned b128 reads, 2-way bank alias = free). Each lane writes its one
// hi + lo fp16 (b16) at [c][8q+w]; reads are 2x ds_read_b128. No K-perm.
// FP16 2-TERM h (hi+lo, 2 chained MFMAs) with single-fp16 weights, verified
// in R2 (absmax 2^-10, same as baseline). Gates pre-scaled by -log2e (i,f,o)
// / +2log2e (g); per-lane scalar cell math: 5 exp2 + 2 rcp.
// s_setprio(1) around MFMA+cell math (T5): 4 waves/SIMD from 2 drifting
// blocks -> priority favors the wave that just cleared the barrier.

#define TT 512
#define HH 32
#define L2E 1.44269504088896340736f
#define XROW 132   // x row stride (floats)
#define HROW 40    // h plane row stride (fp16): 80 B

typedef _Float16 f16x8 __attribute__((ext_vector_type(8)));
typedef float f32x4 __attribute__((ext_vector_type(4)));

__device__ __forceinline__ float fastrcp(float x) { return __builtin_amdgcn_rcpf(x); }
__device__ __forceinline__ float exp2f_(float x) { return __builtin_amdgcn_exp2f(x); }

__launch_bounds__(512, 4)
__global__ void lstm_kernel(const float* __restrict__ x,
                            const float* __restrict__ W_ih,
                            const float* __restrict__ W_hh,
                            const float* __restrict__ b_ih,
                            const float* __restrict__ b_hh,
                            const float* __restrict__ W_fc,
                            const float* __restrict__ b_fc,
                            float* __restrict__ out) {
    __shared__ _Float16 hh[2][16][HROW];   // h hi planes [parity][batch][unit]
    __shared__ _Float16 hl[2][16][HROW];   // h lo planes
    __shared__ float xbuf[16 * XROW];      // x chunk: 16 batches x 128 steps

    const int tid  = threadIdx.x;
    const int lane = tid & 63;
    const int w    = tid >> 6;        // wave 0..7 = tile index
    const int c    = lane & 15;       // batch (MFMA n); also A m-row
    const int q    = lane >> 4;       // quad: k-block 8q; unit-block 8q
    const int base = blockIdx.x * 16;

    // ---- A-fragment (weights) for tile w, single fp16 (R2-verified order) ----
    const int gate = c & 3;
    const float asc = (gate == 2) ? (2.0f * L2E) : (-L2E);
    const int wrow0 = gate * 32 + 8 * (c >> 2);
    f16x8 wa;
    #pragma unroll
    for (int j = 0; j < 8; ++j)
        wa[j] = (_Float16)(W_hh[(wrow0 + w) * HH + 8 * q + j] * asc);

    // ---- per-cell consts: this lane's cell = (unit 8q + w, batch c) ----
    const int u = 8 * q + w;
    f32x4 wih, bcs;
    #pragma unroll
    for (int r = 0; r < 4; ++r) {
        const float sc = (r == 2) ? (2.0f * L2E) : (-L2E);
        wih[r] = W_ih[32 * r + u] * sc;
        bcs[r] = (b_ih[32 * r + u] + b_hh[32 * r + u]) * sc;
    }

    // ---- zero parity-0 planes (h0 = 0) ----
    for (int i = tid; i < 16 * HROW; i += 512) {
        ((_Float16*)hh[0])[i] = (_Float16)0.f;
        ((_Float16*)hl[0])[i] = (_Float16)0.f;
    }

    // ---- stage x chunk 0: 16 rows x 128 floats = 512 float4, 1/thread ----
    const int xr  = tid >> 5;             // 0..15
    const int xc4 = (tid & 31) * 4;       // 0..124
    {
        const float4 v = *(const float4*)&x[(size_t)(base + xr) * TT + xc4];
        *(float4*)&xbuf[xr * XROW + xc4] = v;
    }

    float cs = 0.f;                        // c-state for this lane's cell
    float xc = 0.f;
    f32x4 ai;                              // a-init (wih*x + bias) for step t

    #pragma unroll 1
    for (int t = 0; t < TT; ++t) {
        const int RP = t & 1;
        if ((t & 127) == 0) {
            if (t) {
                // old-chunk reads all completed before prior step's barrier
                const float4 v = *(const float4*)&x[(size_t)(base + xr) * TT + t + xc4];
                *(float4*)&xbuf[xr * XROW + xc4] = v;
            }
            __syncthreads();               // covers staging (and init at t=0)
            xc = xbuf[c * XROW];           // element (t & 127) == 0
            ai = wih * xc + bcs;
        }
        // post-barrier critical path: 2x b128 read -> MFMA (ai precomputed)
        const f16x8 BH = *(const f16x8*)&hh[RP][c][8 * q];
        const f16x8 BL = *(const f16x8*)&hl[RP][c][8 * q];
        __builtin_amdgcn_s_setprio(1);
        f32x4 a = __builtin_amdgcn_mfma_f32_16x16x32_f16(wa, BH, ai, 0, 0, 0);
        a = __builtin_amdgcn_mfma_f32_16x16x32_f16(wa, BL, a, 0, 0, 0);
        const float xn = xbuf[c * XROW + ((t + 1) & 127)];  // prefetch next x
        const float Ei = exp2f_(a[0]);
        const float Ef = exp2f_(a[1]);
        const float G  = exp2f_(a[2]);
        const float Eo = exp2f_(a[3]);
        const float aig = (1.f + Ei) * (G + 1.f);
        const float af  = 1.f + Ef;
        const float num = cs * aig + (G - 1.f) * af;
        const float den = af * aig;
        const float cn  = num * fastrcp(den);
        cs = cn;
        const float ycv = __builtin_amdgcn_fmed3f(cn * (2.0f * L2E), -60.f, 60.f);
        const float C   = exp2f_(ycv);
        const float hden = (C + 1.f) * (1.f + Eo);
        const float hv   = (C - 1.f) * fastrcp(hden);
        __builtin_amdgcn_s_setprio(0);
        const _Float16 ph = (_Float16)hv;
        const _Float16 pl = (_Float16)(hv - (float)ph);
        hh[RP ^ 1][c][u] = ph;             // this lane's cell -> next B-frag slot
        hl[RP ^ 1][c][u] = pl;
        ai = wih * xn + bcs;               // next step's a-init (pre-barrier)
        __syncthreads();
        xc = xn;
    }
    // T=512 even -> final h in parity-0 planes; loop ended with a barrier.

    // ---- head: out[b] = h_T @ W_fc^T + b_fc (wave 0 only) ----
    if (w == 0) {
        const f16x8 BH = *(const f16x8*)&hh[0][c][8 * q];
        const f16x8 BL = *(const f16x8*)&hl[0][c][8 * q];
        float s = 0.f;
        #pragma unroll
        for (int j = 0; j < 8; ++j)
            s += ((float)BH[j] + (float)BL[j]) * W_fc[8 * q + j];
        s += __shfl_xor(s, 16);            // reduce over q
        s += __shfl_xor(s, 32);
        if (lane < 16)
            out[base + lane] = b_fc[0] + s;
    }
}

extern "C" void kernel_launch(void* const* d_in, const int* in_sizes, int n_in,
                              void* d_out, int out_size, void* d_ws, size_t ws_size,
                              hipStream_t stream) {
    const float* x    = (const float*)d_in[0];
    const float* W_ih = (const float*)d_in[1];
    const float* W_hh = (const float*)d_in[2];
    const float* b_ih = (const float*)d_in[3];
    const float* b_hh = (const float*)d_in[4];
    const float* W_fc = (const float*)d_in[5];
    const float* b_fc = (const float*)d_in[6];
    float* out = (float*)d_out;

    const int B = 8192;
    lstm_kernel<<<B / 16, 512, 0, stream>>>(x, W_ih, W_hh, b_ih, b_hh,
                                            W_fc, b_fc, out);
}